// Round 5
// baseline (50.418 us; speedup 1.0000x reference)
//
#include <hip/hip_runtime.h>

// Problem constants: B=2, S=4, N=M=4096, fp32 3D points.
constexpr int Sn = 4;
constexpr int Nn = 4096;
constexpr int Mn = 4096;
constexpr int NS2 = 16;               // (dir,slice): z = dir*8 + slice
constexpr int CH  = 16;               // combine-kernel i-range split

// pmin layout: float [NS2][NBC][Nn]; then sums2[NS2][CH]

template <int APT, int NBC>
__global__ __launch_bounds__(256, 4) void chamfer_partial(
    const float* __restrict__ X,   // output_points [8][4096][3]
    const float* __restrict__ Y,   // target_points [8][4096][3]
    float* __restrict__ pmin)      // [NS2][NBC][Nn]
{
    constexpr int BCHUNK = Mn / NBC;
    constexpr int ATILE  = APT * 256;
    static_assert(APT % 4 == 0, "APT multiple of 4 for float4 A-loads");

    __shared__ float4 ldsB[BCHUNK];

    const int at    = blockIdx.x;
    const int bc    = blockIdx.y;
    const int z     = blockIdx.z;
    const int slice = z & 7;
    const int dir   = z >> 3;
    const int tid   = threadIdx.x;

    const float* A  = (dir == 0 ? X : Y) + slice * (Nn * 3);
    const float* Bp = (dir == 0 ? Y : X) + slice * (Mn * 3) + bc * (BCHUNK * 3);

    // Each thread owns APT CONTIGUOUS rows: n = at*ATILE + tid*APT + j.
    // A-load: 3 float4 per 4 points, fully coalesced (wave reads APT*768B contiguous).
    float ax[APT], ay[APT], az[APT], a2[APT], acc[APT];
    const float4* A4 = (const float4*)(A + (size_t)(at * ATILE + tid * APT) * 3);
    #pragma unroll
    for (int g = 0; g < APT / 4; ++g) {
        float4 q0 = A4[3 * g + 0];
        float4 q1 = A4[3 * g + 1];
        float4 q2 = A4[3 * g + 2];
        float c[12] = {q0.x, q0.y, q0.z, q0.w, q1.x, q1.y, q1.z, q1.w,
                       q2.x, q2.y, q2.z, q2.w};
        #pragma unroll
        for (int k = 0; k < 4; ++k) {
            const int j = 4 * g + k;
            ax[j] = c[3 * k + 0];
            ay[j] = c[3 * k + 1];
            az[j] = c[3 * k + 2];
            a2[j] = ax[j] * ax[j] + ay[j] * ay[j] + az[j] * az[j];
            acc[j] = 3.4e38f;
        }
    }

    // Stage B chunk pre-transformed: (-2bx, -2by, -2bz, |b|^2)
    for (int p = tid; p < BCHUNK; p += 256) {
        float bx = Bp[p * 3 + 0], by = Bp[p * 3 + 1], bz = Bp[p * 3 + 2];
        ldsB[p] = make_float4(-2.0f * bx, -2.0f * by, -2.0f * bz,
                              bx * bx + by * by + bz * bz);
    }
    __syncthreads();

    // 2 ds_read_b128 broadcasts amortized over 2*APT=32 pairs/lane;
    // 3 FMA per pair + v_min3 per 2 pairs.
    #pragma unroll 4
    for (int m = 0; m < BCHUNK; m += 2) {
        float4 b0 = ldsB[m + 0];
        float4 b1 = ldsB[m + 1];
        #pragma unroll
        for (int j = 0; j < APT; ++j) {
            float d0 = fmaf(ax[j], b0.x, fmaf(ay[j], b0.y, fmaf(az[j], b0.z, b0.w)));
            float d1 = fmaf(ax[j], b1.x, fmaf(ay[j], b1.y, fmaf(az[j], b1.z, b1.w)));
            acc[j] = fminf(acc[j], fminf(d0, d1));   // -> v_min3_f32
        }
    }

    // Store partial mins (+|a|^2) as float4: rows contiguous per thread.
    float* dstf = pmin + ((size_t)z * NBC + bc) * Nn + at * ATILE + tid * APT;
    float4* dst4 = (float4*)dstf;
    #pragma unroll
    for (int g = 0; g < APT / 4; ++g) {
        dst4[g] = make_float4(acc[4 * g + 0] + a2[4 * g + 0],
                              acc[4 * g + 1] + a2[4 * g + 1],
                              acc[4 * g + 2] + a2[4 * g + 2],
                              acc[4 * g + 3] + a2[4 * g + 3]);
    }
}

template <int NBC>
__global__ __launch_bounds__(256) void chamfer_combine(
    const float* __restrict__ pmin, float* __restrict__ sums2)  // sums2[NS2][CH]
{
    const int z   = blockIdx.x;       // 0..15
    const int c   = blockIdx.y;       // 0..CH-1
    const int tid = threadIdx.x;
    constexpr int SPAN = Nn / CH;     // 256

    const float* p = pmin + (size_t)z * NBC * Nn;

    float s = 0.0f;
    for (int i = c * SPAN + tid; i < (c + 1) * SPAN; i += 256) {
        float m = p[i];
        #pragma unroll 8
        for (int bc = 1; bc < NBC; ++bc) m = fminf(m, p[(size_t)bc * Nn + i]);
        s += m;
    }

    s += __shfl_down(s, 32);
    s += __shfl_down(s, 16);
    s += __shfl_down(s, 8);
    s += __shfl_down(s, 4);
    s += __shfl_down(s, 2);
    s += __shfl_down(s, 1);

    __shared__ float red[4];
    if ((tid & 63) == 0) red[tid >> 6] = s;
    __syncthreads();
    if (tid == 0) sums2[z * CH + c] = red[0] + red[1] + red[2] + red[3];
}

__global__ __launch_bounds__(64) void chamfer_finalize(
    const float* __restrict__ sums2, float* __restrict__ out)
{
    const int tid = threadIdx.x;
    // total[z] = sum_c sums2[z][c]; z = dir*8 + (b*4 + s)
    __shared__ float tot[NS2];
    if (tid < NS2) {
        float t = 0.0f;
        #pragma unroll
        for (int c = 0; c < CH; ++c) t += sums2[tid * CH + c];
        tot[tid] = t;
    }
    __syncthreads();
    if (tid < 8) {
        const int s = tid >> 1, b = tid & 1;
        const int l = b * Sn + s;
        out[4 + s * 2 + b] = tot[l] * (1.0f / Nn) + tot[8 + l] * (1.0f / Mn);
    } else if (tid < 12) {
        const int s = tid - 8;
        float c0 = tot[0 * Sn + s] * (1.0f / Nn) + tot[8 + 0 * Sn + s] * (1.0f / Mn);
        float c1 = tot[1 * Sn + s] * (1.0f / Nn) + tot[8 + 1 * Sn + s] * (1.0f / Mn);
        out[s] = 0.5f * (c0 + c1);
    }
}

extern "C" void kernel_launch(void* const* d_in, const int* in_sizes, int n_in,
                              void* d_out, int out_size, void* d_ws, size_t ws_size,
                              hipStream_t stream) {
    const float* X = (const float*)d_in[0];   // output_points [2,4,4096,3]
    const float* Y = (const float*)d_in[1];   // target_points [2,4,4096,3]
    float* out  = (float*)d_out;              // 12 floats
    float* pmin = (float*)d_ws;

    const size_t need_main = ((size_t)NS2 * 64 * Nn + NS2 * CH + 64) * sizeof(float);

    if (ws_size >= need_main) {
        // APT=16: 1 ds_read broadcast per 16 rows -> LDS pipe ~5us < VALU ~12us.
        // NBC=64 -> 1024 blocks (4/CU, 4 waves/SIMD with VGPR capped at 128).
        constexpr int APT = 16, NBC = 64;
        float* sums2 = pmin + (size_t)NS2 * NBC * Nn;
        dim3 grid(Nn / (APT * 256), NBC, NS2);            // (1, 64, 16)
        chamfer_partial<APT, NBC><<<grid, 256, 0, stream>>>(X, Y, pmin);
        chamfer_combine<NBC><<<dim3(NS2, CH), 256, 0, stream>>>(pmin, sums2);
        chamfer_finalize<<<1, 64, 0, stream>>>(sums2, out);
    } else {
        // Small-ws fallback (1 MB pmin, proven geometry)
        constexpr int APT = 4, NBC = 4;
        float* sums2 = pmin + (size_t)NS2 * NBC * Nn;
        dim3 grid(Nn / (APT * 256), NBC, NS2);            // (4, 4, 16)
        chamfer_partial<APT, NBC><<<grid, 256, 0, stream>>>(X, Y, pmin);
        chamfer_combine<NBC><<<dim3(NS2, CH), 256, 0, stream>>>(pmin, sums2);
        chamfer_finalize<<<1, 64, 0, stream>>>(sums2, out);
    }
}

// Round 6
// 47.395 us; speedup vs baseline: 1.0638x; 1.0638x over previous
//
#include <hip/hip_runtime.h>

// Problem constants: B=2, S=4, N=M=4096, fp32 3D points.
constexpr int Sn = 4;
constexpr int Nn = 4096;
constexpr int Mn = 4096;
constexpr int NS2 = 16;               // (dir,slice): z = dir*8 + slice
constexpr int CH  = 16;               // combine-kernel i-range split

// pmin layout: float [NS2][NBC][Nn]; then sums2[NS2][CH]

template <int APT, int NBC, int MINWAVES>
__global__ __launch_bounds__(256, MINWAVES) void chamfer_partial(
    const float* __restrict__ X,   // output_points [8][4096][3]
    const float* __restrict__ Y,   // target_points [8][4096][3]
    float* __restrict__ pmin)      // [NS2][NBC][Nn]
{
    constexpr int BCHUNK = Mn / NBC;
    constexpr int ATILE  = APT * 256;

    __shared__ float4 ldsB[BCHUNK];

    const int at    = blockIdx.x;
    const int bc    = blockIdx.y;
    const int z     = blockIdx.z;
    const int slice = z & 7;
    const int dir   = z >> 3;
    const int tid   = threadIdx.x;

    const float* A  = (dir == 0 ? X : Y) + slice * (Nn * 3);
    const float* Bp = (dir == 0 ? Y : X) + slice * (Mn * 3) + bc * (BCHUNK * 3);

    // Register-block APT A-points (strided ownership: n = at*ATILE + j*256 + tid).
    // No a2[] array: |a|^2 recomputed in the epilogue to save 8 VGPRs.
    float ax[APT], ay[APT], az[APT], acc[APT];
    #pragma unroll
    for (int j = 0; j < APT; ++j) {
        const int n = at * ATILE + j * 256 + tid;
        ax[j] = A[n * 3 + 0];
        ay[j] = A[n * 3 + 1];
        az[j] = A[n * 3 + 2];
        acc[j] = 3.4e38f;
    }

    // Stage B chunk pre-transformed: (-2bx, -2by, -2bz, |b|^2)
    for (int p = tid; p < BCHUNK; p += 256) {
        float bx = Bp[p * 3 + 0], by = Bp[p * 3 + 1], bz = Bp[p * 3 + 2];
        ldsB[p] = make_float4(-2.0f * bx, -2.0f * by, -2.0f * bz,
                              bx * bx + by * by + bz * bz);
    }
    __syncthreads();

    // 2 ds_read_b128 broadcasts amortized over 2*APT pairs;
    // 3 FMA per pair + v_min3 per 2 pairs. Unroll 2 keeps b-reg liveness low.
    #pragma unroll 2
    for (int m = 0; m < BCHUNK; m += 2) {
        float4 b0 = ldsB[m + 0];
        float4 b1 = ldsB[m + 1];
        #pragma unroll
        for (int j = 0; j < APT; ++j) {
            float d0 = fmaf(ax[j], b0.x, fmaf(ay[j], b0.y, fmaf(az[j], b0.z, b0.w)));
            float d1 = fmaf(ax[j], b1.x, fmaf(ay[j], b1.y, fmaf(az[j], b1.z, b1.w)));
            acc[j] = fminf(fminf(acc[j], d0), d1);   // -> v_min3_f32
        }
    }

    // Coalesced store of partial mins (+|a|^2, recomputed here)
    float* dst = pmin + ((size_t)z * NBC + bc) * Nn + at * ATILE;
    #pragma unroll
    for (int j = 0; j < APT; ++j) {
        float a2 = ax[j] * ax[j] + ay[j] * ay[j] + az[j] * az[j];
        dst[j * 256 + tid] = acc[j] + a2;
    }
}

template <int NBC>
__global__ __launch_bounds__(256) void chamfer_combine(
    const float* __restrict__ pmin, float* __restrict__ sums2)  // sums2[NS2][CH]
{
    const int z   = blockIdx.x;       // 0..15
    const int c   = blockIdx.y;       // 0..CH-1
    const int tid = threadIdx.x;
    constexpr int SPAN = Nn / CH;     // 256

    const float* p = pmin + (size_t)z * NBC * Nn;

    float s = 0.0f;
    for (int i = c * SPAN + tid; i < (c + 1) * SPAN; i += 256) {
        float m = p[i];
        #pragma unroll 8
        for (int bc = 1; bc < NBC; ++bc) m = fminf(m, p[(size_t)bc * Nn + i]);
        s += m;
    }

    s += __shfl_down(s, 32);
    s += __shfl_down(s, 16);
    s += __shfl_down(s, 8);
    s += __shfl_down(s, 4);
    s += __shfl_down(s, 2);
    s += __shfl_down(s, 1);

    __shared__ float red[4];
    if ((tid & 63) == 0) red[tid >> 6] = s;
    __syncthreads();
    if (tid == 0) sums2[z * CH + c] = red[0] + red[1] + red[2] + red[3];
}

__global__ __launch_bounds__(64) void chamfer_finalize(
    const float* __restrict__ sums2, float* __restrict__ out)
{
    const int tid = threadIdx.x;
    // total[z] = sum_c sums2[z][c]; z = dir*8 + (b*4 + s)
    __shared__ float tot[NS2];
    if (tid < NS2) {
        float t = 0.0f;
        #pragma unroll
        for (int c = 0; c < CH; ++c) t += sums2[tid * CH + c];
        tot[tid] = t;
    }
    __syncthreads();
    if (tid < 8) {
        const int s = tid >> 1, b = tid & 1;
        const int l = b * Sn + s;
        out[4 + s * 2 + b] = tot[l] * (1.0f / Nn) + tot[8 + l] * (1.0f / Mn);
    } else if (tid < 12) {
        const int s = tid - 8;
        float c0 = tot[0 * Sn + s] * (1.0f / Nn) + tot[8 + 0 * Sn + s] * (1.0f / Mn);
        float c1 = tot[1 * Sn + s] * (1.0f / Nn) + tot[8 + 1 * Sn + s] * (1.0f / Mn);
        out[s] = 0.5f * (c0 + c1);
    }
}

extern "C" void kernel_launch(void* const* d_in, const int* in_sizes, int n_in,
                              void* d_out, int out_size, void* d_ws, size_t ws_size,
                              hipStream_t stream) {
    const float* X = (const float*)d_in[0];   // output_points [2,4,4096,3]
    const float* Y = (const float*)d_in[1];   // target_points [2,4,4096,3]
    float* out  = (float*)d_out;              // 12 floats
    float* pmin = (float*)d_ws;

    const size_t need_main = ((size_t)NS2 * 64 * Nn + NS2 * CH + 64) * sizeof(float);

    if (ws_size >= need_main) {
        // APT=8 (proven inner loop), NBC=64 -> BCHUNK=64 (1 KB LDS),
        // grid (2,64,16)=2048 blocks = 8/CU, target 8 waves/SIMD (VGPR<=64).
        constexpr int APT = 8, NBC = 64;
        float* sums2 = pmin + (size_t)NS2 * NBC * Nn;
        dim3 grid(Nn / (APT * 256), NBC, NS2);
        chamfer_partial<APT, NBC, 8><<<grid, 256, 0, stream>>>(X, Y, pmin);
        chamfer_combine<NBC><<<dim3(NS2, CH), 256, 0, stream>>>(pmin, sums2);
        chamfer_finalize<<<1, 64, 0, stream>>>(sums2, out);
    } else {
        // Small-ws fallback (1 MB pmin, proven geometry)
        constexpr int APT = 4, NBC = 4;
        float* sums2 = pmin + (size_t)NS2 * NBC * Nn;
        dim3 grid(Nn / (APT * 256), NBC, NS2);
        chamfer_partial<APT, NBC, 4><<<grid, 256, 0, stream>>>(X, Y, pmin);
        chamfer_combine<NBC><<<dim3(NS2, CH), 256, 0, stream>>>(pmin, sums2);
        chamfer_finalize<<<1, 64, 0, stream>>>(sums2, out);
    }
}